// Round 9
// baseline (267.267 us; speedup 1.0000x reference)
//
#include <hip/hip_runtime.h>

#define NB    16
#define NCH   512
#define NCOL  16384
#define NPTS  4096
#define CHUNK 512          // columns per fused max+sort block
#define NCHK  (NCOL/CHUNK) // 32 chunks per batch

typedef unsigned long long u64;

// Barrier rule for bitonic passes, mapping i ≡ tid (mod NT):
//   j >= NT : pair is same-thread  -> no barrier
//   j <  32 : operands were last written by same-wave threads -> no barrier
//             (per-wave DS ops are program-ordered; HW-validated R3-R8)
//   else    : cross-wave -> __syncthreads()
#define PASS_SYNC_NT(j, NT) do { if ((j) >= 32 && (j) < (NT)) __syncthreads(); } while (0)

__device__ inline unsigned diag_search(const u64* __restrict__ A,
                                       const u64* __restrict__ B,
                                       unsigned p, unsigned L) {
    unsigned lo = (p > L) ? (p - L) : 0u;
    unsigned hi = (p < L) ? p : L;
    while (lo < hi) {
        unsigned mid = (lo + hi) >> 1;
        if (A[mid] < B[p - 1 - mid]) hi = mid; else lo = mid + 1;
    }
    return lo;
}

// ---------------------------------------------------------------------------
// Phase 1 (fused): for a 512-column chunk, z[i] = max_c y[b][c][i], encode
//   key = (sortable_uint(z) << 32) | (16383 - i)   (unique -> total order;
//   desc sort == value desc, index asc == lax.top_k tie-breaking),
// then bitonic-sort the 512 keys descending in LDS and write the sorted run.
// 512 blocks x 128 thr = 1024 waves (same streaming TLP as proven max_key).
// ---------------------------------------------------------------------------
__global__ __launch_bounds__(128) void max_sort_kernel(
        const float* __restrict__ y, u64* __restrict__ keys) {
    __shared__ u64 sk[CHUNK];   // 4 KiB
    unsigned tid = threadIdx.x;
    unsigned ch  = blockIdx.x;          // chunk 0..31
    unsigned b   = blockIdx.y;
    unsigned col = ch * CHUNK + (tid << 2);

    const float* p = y + ((size_t)b << 23) + col;
    float4 m = *(const float4*)p;
    #pragma unroll 8
    for (int c = 1; c < NCH; ++c) {
        float4 v = *(const float4*)(p + ((size_t)c << 14));
        m.x = fmaxf(m.x, v.x); m.y = fmaxf(m.y, v.y);
        m.z = fmaxf(m.z, v.z); m.w = fmaxf(m.w, v.w);
    }
    float mv[4] = {m.x, m.y, m.z, m.w};
    #pragma unroll
    for (int q = 0; q < 4; ++q) {
        unsigned u = __float_as_uint(mv[q]);
        unsigned s = (u & 0x80000000u) ? ~u : (u | 0x80000000u);
        sk[(tid << 2) + q] = ((u64)s << 32) | (u64)(16383u - (col + q));
    }
    __syncthreads();

    // bitonic sort 512 keys descending, 4 elems/thread, i ≡ tid (mod 128)
    for (unsigned k = 2; k <= CHUNK; k <<= 1) {
        for (unsigned j = k >> 1; j > 0; j >>= 1) {
            PASS_SYNC_NT(j, 128);
            #pragma unroll
            for (unsigned s = 0; s < 4; ++s) {
                unsigned i = tid + (s << 7);
                unsigned ixj = i ^ j;
                if (ixj > i) {
                    u64 a = sk[i], c2 = sk[ixj];
                    bool sw = ((i & k) == 0) ? (a < c2) : (a > c2);
                    if (sw) { sk[i] = c2; sk[ixj] = a; }
                }
            }
        }
    }
    __syncthreads();
    u64* gk = keys + ((size_t)b << 14) + (size_t)ch * CHUNK;
    #pragma unroll
    for (unsigned s = 0; s < 4; ++s) gk[tid + (s << 7)] = sk[tid + (s << 7)];
}

// ---------------------------------------------------------------------------
// Phase 2: fused 5-level merge tree, one block/batch (1024 thr, 128 KiB LDS).
// Merge-path at every level (unique keys -> strict compares, exact tie order):
//   L0: 16 tasks (512,512)->1024 full merge,  global -> LDS
//   L1:  8 tasks (1024,1024)->2048 full merge, LDS->regs->LDS (barriered)
//   L2:  4 tasks (2048,2048)->4096 full merge, LDS->regs->LDS
//   L3:  2 tasks top-4096 of (4096,4096),      LDS->regs->LDS (compacting)
//   L4:  1 task  top-4096 of (4096,4096) -> decoded idx (int4 store)
// ---------------------------------------------------------------------------
__global__ __launch_bounds__(1024) void merge_all_kernel(
        const u64* __restrict__ keys, int* __restrict__ idx) {
    __shared__ u64 s0[16384];   // 128 KiB
    unsigned tid = threadIdx.x;
    unsigned bt  = blockIdx.x;
    const u64* gk = keys + ((size_t)bt << 14);

    // ---- L0: global -> LDS
    {
        unsigned task = tid >> 6, t = tid & 63u, p = t << 4;
        const u64* A = gk + (task << 10);
        const u64* B = A + 512;
        unsigned a = diag_search(A, B, p, 512), b = p - a;
        u64 av = (a < 512) ? A[a] : 0ull;
        u64 bv = (b < 512) ? B[b] : 0ull;
        u64* dst = s0 + (task << 10) + p;
        #pragma unroll
        for (unsigned q = 0; q < 16; ++q) {
            bool ta = (b >= 512) || (a < 512 && av > bv);
            u64 o = ta ? av : bv;
            if (ta) { ++a; av = (a < 512) ? A[a] : 0ull; }
            else    { ++b; bv = (b < 512) ? B[b] : 0ull; }
            dst[q] = o;
        }
    }
    __syncthreads();

    // ---- L1: (1024,1024) full merge, in place via regs
    {
        const unsigned L = 1024;
        unsigned task = tid >> 7, t = tid & 127u, p = t << 4;
        const u64* A = s0 + (task << 11);
        const u64* B = A + L;
        unsigned a = diag_search(A, B, p, L), b = p - a;
        u64 r[16];
        u64 av = (a < L) ? A[a] : 0ull;
        u64 bv = (b < L) ? B[b] : 0ull;
        #pragma unroll
        for (unsigned q = 0; q < 16; ++q) {
            bool ta = (b >= L) || (a < L && av > bv);
            r[q] = ta ? av : bv;
            if (ta) { ++a; av = (a < L) ? A[a] : 0ull; }
            else    { ++b; bv = (b < L) ? B[b] : 0ull; }
        }
        __syncthreads();
        u64* dst = s0 + (task << 11) + p;
        #pragma unroll
        for (unsigned q = 0; q < 16; ++q) dst[q] = r[q];
    }
    __syncthreads();

    // ---- L2: (2048,2048) full merge, in place via regs
    {
        const unsigned L = 2048;
        unsigned task = tid >> 8, t = tid & 255u, p = t << 4;
        const u64* A = s0 + (task << 12);
        const u64* B = A + L;
        unsigned a = diag_search(A, B, p, L), b = p - a;
        u64 r[16];
        u64 av = (a < L) ? A[a] : 0ull;
        u64 bv = (b < L) ? B[b] : 0ull;
        #pragma unroll
        for (unsigned q = 0; q < 16; ++q) {
            bool ta = (b >= L) || (a < L && av > bv);
            r[q] = ta ? av : bv;
            if (ta) { ++a; av = (a < L) ? A[a] : 0ull; }
            else    { ++b; bv = (b < L) ? B[b] : 0ull; }
        }
        __syncthreads();
        u64* dst = s0 + (task << 12) + p;
        #pragma unroll
        for (unsigned q = 0; q < 16; ++q) dst[q] = r[q];
    }
    __syncthreads();

    // ---- L3: top-4096 of (4096,4096) x2, compacting to [0,8192)
    {
        const unsigned L = 4096;
        unsigned task = tid >> 9, t = tid & 511u, p = t << 3;
        const u64* A = s0 + (task << 13);
        const u64* B = A + L;
        unsigned a = diag_search(A, B, p, L), b = p - a;
        u64 r[8];
        u64 av = (a < L) ? A[a] : 0ull;
        u64 bv = (b < L) ? B[b] : 0ull;
        #pragma unroll
        for (unsigned q = 0; q < 8; ++q) {
            bool ta = (b >= L) || (a < L && av > bv);
            r[q] = ta ? av : bv;
            if (ta) { ++a; av = (a < L) ? A[a] : 0ull; }
            else    { ++b; bv = (b < L) ? B[b] : 0ull; }
        }
        __syncthreads();
        u64* dst = s0 + (task << 12) + p;
        #pragma unroll
        for (unsigned q = 0; q < 8; ++q) dst[q] = r[q];
    }
    __syncthreads();

    // ---- L4: top-4096 of (4096,4096) -> decoded idx
    {
        const unsigned L = 4096;
        unsigned p = tid << 2;
        const u64* A = s0;
        const u64* B = s0 + L;
        unsigned a = diag_search(A, B, p, L), b = p - a;
        u64 av = (a < L) ? A[a] : 0ull;
        u64 bv = (b < L) ? B[b] : 0ull;
        int o4[4];
        #pragma unroll
        for (unsigned q = 0; q < 4; ++q) {
            bool ta = (b >= L) || (a < L && av > bv);
            u64 o = ta ? av : bv;
            if (ta) { ++a; av = (a < L) ? A[a] : 0ull; }
            else    { ++b; bv = (b < L) ? B[b] : 0ull; }
            o4[q] = (int)(16383u - (unsigned)(o & 0xFFFFFFFFull));
        }
        *(int4*)(idx + ((size_t)bt << 12) + p) =
            make_int4(o4[0], o4[1], o4[2], o4[3]);
    }
}

// ---------------------------------------------------------------------------
// Phase 3: LDS-staged row gather: 1024 thr + 64 KiB LDS -> 2 blocks/CU.
// Both global sides fully coalesced.
// ---------------------------------------------------------------------------
__global__ __launch_bounds__(1024) void row_gather_kernel(
        const float* __restrict__ src, const int* __restrict__ idx,
        float* __restrict__ out, int nch) {
    __shared__ float row[NCOL];   // 64 KiB
    unsigned bc = blockIdx.x;             // b*nch + c
    unsigned b  = bc / (unsigned)nch;
    const float4* sv = (const float4*)(src + ((size_t)bc << 14));
    float4* rv = (float4*)row;
    #pragma unroll
    for (unsigned i = threadIdx.x; i < NCOL / 4; i += 1024) rv[i] = sv[i];
    __syncthreads();
    const int* ib = idx + (b << 12);
    float* orow = out + (size_t)bc * NPTS;
    unsigned j = threadIdx.x << 2;
    int4 iv = *(const int4*)(ib + j);
    float4 ov;
    ov.x = row[iv.x]; ov.y = row[iv.y];
    ov.z = row[iv.z]; ov.w = row[iv.w];
    *(float4*)(orow + j) = ov;
}

extern "C" void kernel_launch(void* const* d_in, const int* in_sizes, int n_in,
                              void* d_out, int out_size, void* d_ws, size_t ws_size,
                              hipStream_t stream) {
    const float* x = (const float*)d_in[0];
    const float* y = (const float*)d_in[1];
    float* out = (float*)d_out;

    char* ws = (char*)d_ws;
    u64* keys = (u64*)ws;                 // 2 MiB
    int* idx  = (int*)(ws + (4u << 20));  // 256 KiB

    // 1) fused channel-max + 512-chunk sort (512 blocks, full machine)
    max_sort_kernel<<<dim3(NCHK, NB), 128, 0, stream>>>(y, keys);
    // 2) fused 5-level merge tree -> idx (16 blocks)
    merge_all_kernel<<<NB, 1024, 0, stream>>>(keys, idx);
    // 3) gathers (both sides coalesced via LDS staging)
    row_gather_kernel<<<NB * 3, 1024, 0, stream>>>(x, idx, out, 3);
    row_gather_kernel<<<NB * NCH, 1024, 0, stream>>>(
        y, idx, out + (size_t)NB * 3 * NPTS, NCH);
}

// Round 10
// 248.141 us; speedup vs baseline: 1.0771x; 1.0771x over previous
//
#include <hip/hip_runtime.h>

#define NB    16
#define NCH   512
#define NCOL  16384
#define NPTS  4096

typedef unsigned long long u64;

// Barrier rule for bitonic passes, element mapping i ≡ tid (mod 1024):
//   j >= 1024 : pair is same-thread          -> no barrier
//   j <  64   : partner thread in same wave  -> no barrier (per-wave DS
//               ops are processed in order — HW-validated R3-R9, absmax 0)
//   else      : cross-wave -> __syncthreads(). Conservative lower edge 32.
#define PASS_SYNC(j) do { if ((j) >= 32 && (j) < 1024) __syncthreads(); } while (0)

// ---------------------------------------------------------------------------
// Phase 1: z[b][i] = max_c y[b][c][i] as 64-bit descending key:
//   key = (sortable_uint(z) << 32) | (16383 - i)   (unique -> total order;
//   desc sort == value desc, index asc == lax.top_k tie-breaking)
// R8-proven form; unroll 16 for deeper outstanding-load pipeline.
// ---------------------------------------------------------------------------
__global__ void max_key_kernel(const float* __restrict__ y,
                               u64* __restrict__ keys) {
    unsigned t = blockIdx.x * 256u + threadIdx.x;   // 0..4095 per batch
    unsigned b = blockIdx.y;
    unsigned i = t << 2;
    const float* p = y + ((size_t)b << 23) + i;
    float4 m = *(const float4*)p;
    #pragma unroll 16
    for (int c = 1; c < NCH; ++c) {
        float4 v = *(const float4*)(p + ((size_t)c << 14));
        m.x = fmaxf(m.x, v.x); m.y = fmaxf(m.y, v.y);
        m.z = fmaxf(m.z, v.z); m.w = fmaxf(m.w, v.w);
    }
    u64* kp = keys + ((size_t)b << 14) + i;
    float mv[4] = {m.x, m.y, m.z, m.w};
    #pragma unroll
    for (int q = 0; q < 4; ++q) {
        unsigned u = __float_as_uint(mv[q]);
        unsigned s = (u & 0x80000000u) ? ~u : (u | 0x80000000u);
        kp[q] = ((u64)s << 32) | (u64)(16383u - (i + q));
    }
}

// ---------------------------------------------------------------------------
// Phase 2a: sort each 2048-chunk descending (bitonic, LDS), in place.
// 8 chunks/batch x 16 batches = 128 blocks. (R8-proven, unchanged.)
// ---------------------------------------------------------------------------
__global__ __launch_bounds__(1024) void chunk_sort_kernel(
        u64* __restrict__ keys) {
    __shared__ u64 sk[2048];   // 16 KiB
    unsigned tid = threadIdx.x;
    unsigned b = blockIdx.x >> 3, ch = blockIdx.x & 7;
    u64* gk = keys + ((size_t)b << 14) + ((size_t)ch << 11);

    sk[tid] = gk[tid];
    sk[tid + 1024] = gk[tid + 1024];
    __syncthreads();
    for (unsigned k = 2; k <= 2048; k <<= 1) {
        for (unsigned j = k >> 1; j > 0; j >>= 1) {
            PASS_SYNC(j);
            #pragma unroll
            for (unsigned s = 0; s < 2; ++s) {
                unsigned i = tid + (s << 10);
                unsigned ixj = i ^ j;
                if (ixj > i) {
                    u64 a = sk[i], c2 = sk[ixj];
                    bool sw = ((i & k) == 0) ? (a < c2) : (a > c2);
                    if (sw) { sk[i] = c2; sk[ixj] = a; }
                }
            }
        }
    }
    __syncthreads();
    gk[tid] = sk[tid];
    gk[tid + 1024] = sk[tid + 1024];
}

// ---------------------------------------------------------------------------
// Phase 2b: fused 3-level merge tree, one block per batch (1024 thr,
// 128 KiB LDS). Merge-path at every level (unique keys -> strict compares,
// exact lax.top_k tie order). (R8-proven, unchanged.)
//   L1: 4 tasks (2048,2048)->4096 full merge, global keys -> LDS
//   L2: 2 tasks top-4096 of (4096,4096), LDS -> regs -> LDS (barriered)
//   L3: 1 task  top-4096 of (4096,4096), LDS -> decoded idx (int4 store)
// ---------------------------------------------------------------------------
__global__ __launch_bounds__(1024) void merge_all_kernel(
        const u64* __restrict__ keys, int* __restrict__ idx) {
    __shared__ u64 s0[16384];   // 128 KiB
    unsigned tid = threadIdx.x;
    unsigned bt  = blockIdx.x;
    const u64* gk = keys + ((size_t)bt << 14);

    // ---- L1: global -> LDS, full merges
    {
        unsigned task = tid >> 8;              // 0..3
        unsigned t    = tid & 255u;
        const unsigned L = 2048;
        const u64* A = gk + (task << 12);
        const u64* B = A + L;
        unsigned p = t << 4;                   // 16 outputs/thread
        unsigned lo = (p > L) ? (p - L) : 0u;
        unsigned hi = (p < L) ? p : L;
        while (lo < hi) {
            unsigned mid = (lo + hi) >> 1;
            if (A[mid] < B[p - 1 - mid]) hi = mid; else lo = mid + 1;
        }
        unsigned a = lo, b = p - lo;
        u64 av = (a < L) ? A[a] : 0ull;
        u64 bv = (b < L) ? B[b] : 0ull;
        u64* dst = s0 + (task << 12) + p;
        #pragma unroll
        for (unsigned q = 0; q < 16; ++q) {
            bool ta = (b >= L) || (a < L && av > bv);
            u64 o = ta ? av : bv;
            if (ta) { ++a; av = (a < L) ? A[a] : 0ull; }
            else    { ++b; bv = (b < L) ? B[b] : 0ull; }
            dst[q] = o;
        }
    }
    __syncthreads();

    // ---- L2: LDS -> regs (top-4096 per task), then barriered write-back
    u64 r[8];
    unsigned task2 = tid >> 9;                 // 0..1
    unsigned t2    = tid & 511u;
    {
        const unsigned L = 4096;
        const u64* A = s0 + (task2 << 13);
        const u64* B = A + L;
        unsigned p = t2 << 3;                  // 8 outputs/thread
        unsigned lo = (p > L) ? (p - L) : 0u;
        unsigned hi = (p < L) ? p : L;
        while (lo < hi) {
            unsigned mid = (lo + hi) >> 1;
            if (A[mid] < B[p - 1 - mid]) hi = mid; else lo = mid + 1;
        }
        unsigned a = lo, b = p - lo;
        u64 av = (a < L) ? A[a] : 0ull;
        u64 bv = (b < L) ? B[b] : 0ull;
        #pragma unroll
        for (unsigned q = 0; q < 8; ++q) {
            bool ta = (b >= L) || (a < L && av > bv);
            r[q] = ta ? av : bv;
            if (ta) { ++a; av = (a < L) ? A[a] : 0ull; }
            else    { ++b; bv = (b < L) ? B[b] : 0ull; }
        }
    }
    __syncthreads();                            // all reads done
    {
        u64* dst = s0 + (task2 << 12) + (t2 << 3);
        #pragma unroll
        for (unsigned q = 0; q < 8; ++q) dst[q] = r[q];
    }
    __syncthreads();                            // all writes visible

    // ---- L3: LDS -> decoded idx
    {
        const unsigned L = 4096;
        const u64* A = s0;
        const u64* B = s0 + L;
        unsigned p = tid << 2;                  // 4 outputs/thread
        unsigned lo = (p > L) ? (p - L) : 0u;
        unsigned hi = (p < L) ? p : L;
        while (lo < hi) {
            unsigned mid = (lo + hi) >> 1;
            if (A[mid] < B[p - 1 - mid]) hi = mid; else lo = mid + 1;
        }
        unsigned a = lo, b = p - lo;
        u64 av = (a < L) ? A[a] : 0ull;
        u64 bv = (b < L) ? B[b] : 0ull;
        int o4[4];
        #pragma unroll
        for (unsigned q = 0; q < 4; ++q) {
            bool ta = (b >= L) || (a < L && av > bv);
            u64 o = ta ? av : bv;
            if (ta) { ++a; av = (a < L) ? A[a] : 0ull; }
            else    { ++b; bv = (b < L) ? B[b] : 0ull; }
            o4[q] = (int)(16383u - (unsigned)(o & 0xFFFFFFFFull));
        }
        *(int4*)(idx + ((size_t)bt << 12) + p) =
            make_int4(o4[0], o4[1], o4[2], o4[3]);
    }
}

// ---------------------------------------------------------------------------
// Phase 3: combined x+y LDS-staged row gather, single launch.
// Blocks [0,48): x rows (b = bc/3), out row bc.
// Blocks [48, 48+8192): y rows t = bc-48 (b = t>>9), out row 192*1024 + t.
// Body identical to the R8-proven row_gather: load 64 KiB row coalesced to
// LDS, gather 4096 (2-way-conflict LDS reads ~free), write float4 coalesced.
// ---------------------------------------------------------------------------
__global__ __launch_bounds__(1024) void all_gather_kernel(
        const float* __restrict__ x, const float* __restrict__ y,
        const int* __restrict__ idx, float* __restrict__ out) {
    __shared__ float row[NCOL];   // 64 KiB
    unsigned bc = blockIdx.x;
    const float* src;
    float* orow;
    unsigned b;
    if (bc < 48u) {                         // x row
        b = bc / 3u;
        src = x + ((size_t)bc << 14);
        orow = out + (size_t)bc * NPTS;
    } else {                                // y row
        unsigned t = bc - 48u;
        b = t >> 9;
        src = y + ((size_t)t << 14);
        orow = out + (size_t)NB * 3 * NPTS + (size_t)t * NPTS;
    }
    const float4* sv = (const float4*)src;
    float4* rv = (float4*)row;
    #pragma unroll
    for (unsigned i = threadIdx.x; i < NCOL / 4; i += 1024) rv[i] = sv[i];
    __syncthreads();
    const int* ib = idx + (b << 12);
    unsigned j = threadIdx.x << 2;
    int4 iv = *(const int4*)(ib + j);
    float4 ov;
    ov.x = row[iv.x]; ov.y = row[iv.y];
    ov.z = row[iv.z]; ov.w = row[iv.w];
    *(float4*)(orow + j) = ov;
}

extern "C" void kernel_launch(void* const* d_in, const int* in_sizes, int n_in,
                              void* d_out, int out_size, void* d_ws, size_t ws_size,
                              hipStream_t stream) {
    const float* x = (const float*)d_in[0];
    const float* y = (const float*)d_in[1];
    float* out = (float*)d_out;

    char* ws = (char*)d_ws;
    u64* keys = (u64*)ws;                 // 2 MiB
    int* idx  = (int*)(ws + (4u << 20));  // 256 KiB

    // 1) per-column channel max -> u64 keys
    max_key_kernel<<<dim3(NCOL / 4 / 256, NB), 256, 0, stream>>>(y, keys);
    // 2) sort 2048-chunks descending in place (128 blocks)
    chunk_sort_kernel<<<NB * 8, 1024, 0, stream>>>(keys);
    // 3) fused 3-level merge tree -> idx (16 blocks)
    merge_all_kernel<<<NB, 1024, 0, stream>>>(keys, idx);
    // 4) single combined gather (48 x-blocks + 8192 y-blocks)
    all_gather_kernel<<<48 + NB * NCH, 1024, 0, stream>>>(x, y, idx, out);
}